// Round 15
// baseline (35.968 us; speedup 1.0000x reference)
//
#include <hip/hip_runtime.h>
#include <math.h>

#define N_HALF 4096
#define D 64
#define M_TOT 8192
#define NPAIR 2080  // 64*65/2 upper-triangle 128x128 tile pairs

typedef _Float16 half8 __attribute__((ext_vector_type(8)));
typedef float f32x4 __attribute__((ext_vector_type(4)));

// Device-global scratch. Fh/g_norms/g_part fully rewritten each call.
// g_colsum/g_ssq: zero at load; prep accumulates (atomics), mmd_out resets
// to zero at the end of every call -> every call starts from zeros.
// R9 lesson: no per-block device fences / ticket counters.
__device__ _Float16 Fh[M_TOT * D];  // 1 MB fragment-major fp16 data
__device__ float g_norms[M_TOT];    // exact fp32 row norms
__device__ float g_colsum[D];       // global column sums (atomic)
__device__ float g_ssq;             // global sum of squares (atomic)
__device__ double g_part[NPAIR];    // per-pair signed partial sums

// Prep: fp16 convert into MFMA fragment-major layout + exact fp32 row norms
// + atomic accumulation of column sums / sum-of-squares (bandwidth inputs).
// Wave w covers k-half s = w&1 only -> cs[w] valid only in [s*32, s*32+32).
// F[rt][s][lane][e] = X[rt*16 + (lane&15)][s*32 + (lane>>4)*8 + e]
__global__ __launch_bounds__(256) void mmd_prep(const float* __restrict__ src,
                                                const float* __restrict__ tgt) {
    __shared__ float cs[4][D];  // per-wave column partials (half-valid each)
    __shared__ float hn[4][16];
    int t = threadIdx.x;
    int tid = blockIdx.x * 256 + t;  // 65536 threads total
    int l = t & 63;
    int rs = tid >> 6;
    int s = rs & 1, rt = rs >> 1;    // uniform per wave; s == (t>>6)&1
    int row = rt * 16 + (l & 15);
    int k0 = s * 32 + (l >> 4) * 8;
    const float* X = (row < N_HALF) ? src + (size_t)row * D
                                    : tgt + (size_t)(row - N_HALF) * D;
    float4 v0 = ((const float4*)(X + k0))[0];
    float4 v1 = ((const float4*)(X + k0))[1];
    float vs[8] = {v0.x, v0.y, v0.z, v0.w, v1.x, v1.y, v1.z, v1.w};
    half8 h;
    float p = 0.f;
#pragma unroll
    for (int e = 0; e < 8; ++e) {
        h[e] = (_Float16)vs[e];  // RNE
        p += vs[e] * vs[e];
    }
    ((half8*)Fh)[tid] = h;
    int w = t >> 6;
    // Column partials: reduce vs[e] over the 16 lanes sharing (l>>4) group.
    {
        float ce[8];
#pragma unroll
        for (int e = 0; e < 8; ++e) ce[e] = vs[e];
#pragma unroll
        for (int off = 1; off < 16; off <<= 1)
#pragma unroll
            for (int e = 0; e < 8; ++e) ce[e] += __shfl_xor(ce[e], off, 64);
        if ((l & 15) == 0)
#pragma unroll
            for (int e = 0; e < 8; ++e) cs[w][k0 + e] = ce[e];
    }
    // Row norms: lanes l, l+16, l+32, l+48 share (row, s-half)
    p += __shfl_down(p, 32, 64);
    p += __shfl_down(p, 16, 64);
    if (l < 16) hn[w][l] = p;
    __syncthreads();
    if (t < 64) {
        float nr = 0.f;
        int tile = t >> 4, r = t & 15;
        if (t < 32) {
            nr = hn[tile * 2][r] + hn[tile * 2 + 1][r];
            g_norms[(blockIdx.x * 2 + tile) * 16 + r] = nr;
        }
        nr += __shfl_down(nr, 32, 64);
        nr += __shfl_down(nr, 16, 64);
        nr += __shfl_down(nr, 8, 64);
        nr += __shfl_down(nr, 4, 64);
        nr += __shfl_down(nr, 2, 64);
        nr += __shfl_down(nr, 1, 64);
        if (t == 0) atomicAdd(&g_ssq, nr);
    }
    if (t < D) {
        // Columns 0-31 live in waves 0,2 (s=0); columns 32-63 in waves 1,3.
        float col = (t < 32) ? (cs[0][t] + cs[2][t]) : (cs[1][t] + cs[3][t]);
        atomicAdd(&g_colsum[t], col);
    }
}

static __device__ inline void decode_pair(int id, int& bi, int& bj) {
    bi = (int)(64.5f - sqrtf(4160.25f - 2.0f * (float)id));
    while ((64 * (bi + 1) - ((bi + 1) * bi) / 2) <= id) ++bi;
    while ((64 * bi - (bi * (bi - 1)) / 2) > id) --bi;
    bj = bi + (id - (64 * bi - (bi * (bi - 1)) / 2));
}

// Main: one 128x128 pair tile per block, 8 waves of 64x32 each.
// g0 derived per block from the FINAL 65 bandwidth floats (64-lane load +
// 6-shuffle butterfly, ~250 cyc, overlaps fragment loads) -- no bw node.
// XCD-chunked pair mapping: contiguous run of 260 pair-ids per XCD.
__global__ __launch_bounds__(512) void mmd_main() {
    __shared__ float sred[8];
    int t = threadIdx.x, w = t >> 6, l = t & 63;
    int wr = w >> 2, wc = w & 3;  // 2x4 wave grid: 64 rows x 32 cols per wave
    const half8* FH = (const half8*)Fh;

    // Bandwidth coefficient from final colsum/ssq (lane-parallel, cheap).
    float cv = g_colsum[l];
    float s2 = cv * cv;
#pragma unroll
    for (int off = 32; off; off >>= 1) s2 += __shfl_xor(s2, off, 64);
    float ssq = g_ssq;
    const float M = (float)M_TOT;
    float sumL2 = 2.f * M * ssq - 2.f * s2;
    float bwq = sumL2 / (M * M - M) * 0.25f;  // / KERNEL_MUL^(KERNEL_NUM//2)
    float g0 = -1.4426950408889634f / (bwq * 16.f);
    float c2 = -2.f * g0;

    int id = (blockIdx.x & 7) * 260 + (blockIdx.x >> 3);  // XCD-chunked (bijective)
    int bi, bj;
    decode_pair(id, bi, bj);

    // Norm loads issued early, pre-scaled by g0 (consumed in epilogue).
    float nas[4][4];
#pragma unroll
    for (int m = 0; m < 4; ++m) {
        float4 v = *(const float4*)&g_norms[bi * 128 + wr * 64 + m * 16 + (l >> 4) * 4];
        nas[m][0] = v.x * g0; nas[m][1] = v.y * g0;
        nas[m][2] = v.z * g0; nas[m][3] = v.w * g0;
    }
    float nbv[2];
#pragma unroll
    for (int n = 0; n < 2; ++n)
        nbv[n] = g_norms[bj * 128 + wc * 32 + n * 16 + (l & 15)] * g0;

    f32x4 acc[4][2] = {};
#pragma unroll
    for (int s = 0; s < 2; ++s) {
        half8 bh[2];
#pragma unroll
        for (int n = 0; n < 2; ++n)
            bh[n] = FH[((bj * 8 + wc * 2 + n) * 2 + s) * 64 + l];
#pragma unroll
        for (int m = 0; m < 4; ++m) {
            half8 ah = FH[((bi * 8 + wr * 4 + m) * 2 + s) * 64 + l];
#pragma unroll
            for (int n = 0; n < 2; ++n)
                acc[m][n] = __builtin_amdgcn_mfma_f32_16x16x32_f16(ah, bh[n], acc[m][n], 0, 0, 0);
        }
    }

    // Epilogue: K_sum over 5 bandwidths via 1 exp2 + 3 muls + fma-folded k0.
    float part4[4] = {0.f, 0.f, 0.f, 0.f};
#pragma unroll
    for (int m = 0; m < 4; ++m)
#pragma unroll
        for (int n = 0; n < 2; ++n)
#pragma unroll
            for (int r = 0; r < 4; ++r) {
                float t0 = fmaf(acc[m][n][r], c2, nas[m][r] + nbv[n]);
                float k4 = __builtin_amdgcn_exp2f(t0);
                float k3 = k4 * k4;
                float k2 = k3 * k3;
                float k1 = k2 * k2;
                float s5 = fmaf(k1, k1, (k4 + k3) + (k2 + k1));  // k0 folded
                part4[r] += s5;
            }
    float part = (part4[0] + part4[1]) + (part4[2] + part4[3]);

#pragma unroll
    for (int off = 32; off; off >>= 1) part += __shfl_down(part, off, 64);
    if (l == 0) sred[w] = part;
    __syncthreads();
    if (t == 0) {
        float tot = ((sred[0] + sred[1]) + (sred[2] + sred[3])) +
                    ((sred[4] + sred[5]) + (sred[6] + sred[7]));
        float sgn = ((bi < 32) == (bj < 32)) ? 1.f : -1.f;
        float scl = (bi == bj) ? 1.f : 2.f;
        g_part[id] = (double)tot * (double)(sgn * scl);
    }
}

// Deterministic tree reduce of the 2080 per-pair doubles + reset of the
// atomic accumulators (so the next call starts from zeros).
__global__ __launch_bounds__(256) void mmd_out(float* __restrict__ out) {
    __shared__ double wred[4];
    int t = threadIdx.x;
    double s = 0.0;
    for (int i = t; i < NPAIR; i += 256) s += g_part[i];
#pragma unroll
    for (int off = 32; off; off >>= 1) s += __shfl_down(s, off, 64);
    if ((t & 63) == 0) wred[t >> 6] = s;
    __syncthreads();
    if (t < D) g_colsum[t] = 0.f;   // restore for next call
    if (t == D) g_ssq = 0.f;
    if (t == 0)
        out[0] = (float)((wred[0] + wred[1] + wred[2] + wred[3]) * (1.0 / 16777216.0));
}

extern "C" void kernel_launch(void* const* d_in, const int* in_sizes, int n_in,
                              void* d_out, int out_size, void* d_ws, size_t ws_size,
                              hipStream_t stream) {
    const float* src = (const float*)d_in[0];
    const float* tgt = (const float*)d_in[1];
    float* out = (float*)d_out;

    mmd_prep<<<256, 256, 0, stream>>>(src, tgt);
    mmd_main<<<NPAIR, 512, 0, stream>>>();
    mmd_out<<<1, 256, 0, stream>>>(out);
}

// Round 16
// 34.790 us; speedup vs baseline: 1.0339x; 1.0339x over previous
//
#include <hip/hip_runtime.h>
#include <math.h>

#define N_HALF 4096
#define D 64
#define M_TOT 8192
#define NPAIR 2080  // 64*65/2 upper-triangle 128x128 tile pairs

typedef _Float16 half8 __attribute__((ext_vector_type(8)));
typedef float f32x4 __attribute__((ext_vector_type(4)));

#define GLOAD16(gp, lp)                                        \
    __builtin_amdgcn_global_load_lds(                          \
        (const __attribute__((address_space(1))) void*)(gp),   \
        (__attribute__((address_space(3))) void*)(lp), 16, 0, 0)

// Device-global scratch (fully rewritten by plain stores every call).
// R9 lesson: no per-block device fences / ticket counters.
__device__ _Float16 Fh[M_TOT * D];  // 1 MB fragment-major fp16 data
__device__ float g_norms[M_TOT];    // exact fp32 row norms
__device__ float g_pssq[256];       // per-prep-block sum-of-squares partials
__device__ float g_pcol[256 * D];   // per-prep-block column-sum partials
__device__ float g_coef;            // base exp2 coefficient g0
__device__ double g_part[NPAIR];    // per-pair signed partial sums

// Prep: fp16 convert into MFMA fragment-major layout + exact fp32 row norms
// + block partials for the bandwidth (wave-shuffle colsums; R14 form).
// Wave w covers k-half s = w&1 only -> cs[w] valid only in [s*32, s*32+32).
// F[rt][s][lane][e] = X[rt*16 + (lane&15)][s*32 + (lane>>4)*8 + e]
__global__ __launch_bounds__(256) void mmd_prep(const float* __restrict__ src,
                                                const float* __restrict__ tgt) {
    __shared__ float cs[4][D];  // per-wave column partials (half-valid each)
    __shared__ float hn[4][16];
    int t = threadIdx.x;
    int tid = blockIdx.x * 256 + t;  // 65536 threads total
    int l = t & 63;
    int rs = tid >> 6;
    int s = rs & 1, rt = rs >> 1;    // uniform per wave; s == (t>>6)&1
    int row = rt * 16 + (l & 15);
    int k0 = s * 32 + (l >> 4) * 8;
    const float* X = (row < N_HALF) ? src + (size_t)row * D
                                    : tgt + (size_t)(row - N_HALF) * D;
    float4 v0 = ((const float4*)(X + k0))[0];
    float4 v1 = ((const float4*)(X + k0))[1];
    float vs[8] = {v0.x, v0.y, v0.z, v0.w, v1.x, v1.y, v1.z, v1.w};
    half8 h;
    float p = 0.f;
#pragma unroll
    for (int e = 0; e < 8; ++e) {
        h[e] = (_Float16)vs[e];  // RNE
        p += vs[e] * vs[e];
    }
    ((half8*)Fh)[tid] = h;
    int w = t >> 6;
    // Column partials: reduce vs[e] over the 16 lanes sharing (l>>4) group.
    {
        float ce[8];
#pragma unroll
        for (int e = 0; e < 8; ++e) ce[e] = vs[e];
#pragma unroll
        for (int off = 1; off < 16; off <<= 1)
#pragma unroll
            for (int e = 0; e < 8; ++e) ce[e] += __shfl_xor(ce[e], off, 64);
        if ((l & 15) == 0)
#pragma unroll
            for (int e = 0; e < 8; ++e) cs[w][k0 + e] = ce[e];
    }
    // Row norms: lanes l, l+16, l+32, l+48 share (row, s-half)
    p += __shfl_down(p, 32, 64);
    p += __shfl_down(p, 16, 64);
    if (l < 16) hn[w][l] = p;
    __syncthreads();
    if (t < 64) {
        float nr = 0.f;
        int tile = t >> 4, r = t & 15;
        if (t < 32) {
            nr = hn[tile * 2][r] + hn[tile * 2 + 1][r];
            g_norms[(blockIdx.x * 2 + tile) * 16 + r] = nr;
        }
        nr += __shfl_down(nr, 32, 64);
        nr += __shfl_down(nr, 16, 64);
        nr += __shfl_down(nr, 8, 64);
        nr += __shfl_down(nr, 4, 64);
        nr += __shfl_down(nr, 2, 64);
        nr += __shfl_down(nr, 1, 64);
        if (t == 0) g_pssq[blockIdx.x] = nr;
    }
    if (t < D) {
        // Columns 0-31 live in waves 0,2 (s=0); columns 32-63 in waves 1,3.
        float col = (t < 32) ? (cs[0][t] + cs[2][t]) : (cs[1][t] + cs[3][t]);
        g_pcol[blockIdx.x * D + t] = col;
    }
}

// Bandwidth coefficient, one small block (R14 form -- per-block fusion
// regressed twice, R12/R15).
__global__ __launch_bounds__(256) void mmd_bw() {
    __shared__ float scol[4][64];
    __shared__ float sssq[4];
    int t = threadIdx.x, w = t >> 6, l = t & 63;
    float csum = 0.f;
#pragma unroll 16
    for (int q = 0; q < 64; ++q) csum += g_pcol[(w * 64 + q) * 64 + l];
    float sq = g_pssq[w * 64 + l];
#pragma unroll
    for (int off = 32; off; off >>= 1) sq += __shfl_xor(sq, off, 64);
    scol[w][l] = csum;
    if (l == 0) sssq[w] = sq;
    __syncthreads();
    if (t < 64) {
        float colsum = (scol[0][l] + scol[1][l]) + (scol[2][l] + scol[3][l]);
        float s2 = colsum * colsum;
#pragma unroll
        for (int off = 32; off; off >>= 1) s2 += __shfl_xor(s2, off, 64);
        if (t == 0) {
            float ssq = (sssq[0] + sssq[1]) + (sssq[2] + sssq[3]);
            const float M = (float)M_TOT;
            float sumL2 = 2.f * M * ssq - 2.f * s2;
            float bwq = sumL2 / (M * M - M) * 0.25f;  // / KERNEL_MUL^2
            g_coef = -1.4426950408889634f / (bwq * 16.f);
        }
    }
}

static __device__ inline void decode_pair(int id, int& bi, int& bj) {
    bi = (int)(64.5f - sqrtf(4160.25f - 2.0f * (float)id));
    while ((64 * (bi + 1) - ((bi + 1) * bi) / 2) <= id) ++bi;
    while ((64 * bi - (bi * (bi - 1)) / 2) > id) --bi;
    bj = bi + (id - (64 * bi - (bi * (bi - 1)) / 2));
}

// Main (R14 + LDS panel staging): one 128x128 pair per block, 8 waves of
// 64x32. The unique A/B panels (16 KB each, contiguous in fragment-major)
// are staged once via linear global_load_lds width-16; waves then read
// fragments from LDS (contiguous 1KB/wave ds_read_b128, conflict-free)
// instead of 3x-redundant L2 traffic. XCD-chunked pair mapping kept.
__global__ __launch_bounds__(512) void mmd_main() {
    __shared__ _Float16 sF[2 * 8192];  // [0,16KB): A panel; [16KB,32KB): B
    __shared__ float sred[8];
    int t = threadIdx.x, w = t >> 6, l = t & 63;
    int wr = w >> 2, wc = w & 3;  // 2x4 wave grid: 64 rows x 32 cols per wave

    int id = (blockIdx.x & 7) * 260 + (blockIdx.x >> 3);  // XCD-chunked (bijective)
    int bi, bj;
    decode_pair(id, bi, bj);

    // Stage A+B panels (4 x 8KB rounds, dest = wave-uniform base + lane*16).
    {
        const char* gA = (const char*)Fh + (size_t)bi * 16384;
        const char* gB = (const char*)Fh + (size_t)bj * 16384;
        char* lp = (char*)sF;
        int off = t * 16;
        GLOAD16(gA + off, lp + off);
        GLOAD16(gA + off + 8192, lp + off + 8192);
        GLOAD16(gB + off, lp + off + 16384);
        GLOAD16(gB + off + 8192, lp + off + 24576);
    }

    // Overlap: g0 + norm loads from global while staging is in flight.
    float g0 = g_coef;
    float c2 = -2.f * g0;
    float nas[4][4];
#pragma unroll
    for (int m = 0; m < 4; ++m) {
        float4 v = *(const float4*)&g_norms[bi * 128 + wr * 64 + m * 16 + (l >> 4) * 4];
        nas[m][0] = v.x * g0; nas[m][1] = v.y * g0;
        nas[m][2] = v.z * g0; nas[m][3] = v.w * g0;
    }
    float nbv[2];
#pragma unroll
    for (int n = 0; n < 2; ++n)
        nbv[n] = g_norms[bj * 128 + wc * 32 + n * 16 + (l & 15)] * g0;

    __syncthreads();  // staging complete (vmcnt(0) drained by compiler)

    const half8* SA = (const half8*)sF;
    const half8* SB = (const half8*)(sF + 8192);

    f32x4 acc[4][2] = {};
#pragma unroll
    for (int s = 0; s < 2; ++s) {
        half8 bh[2];
#pragma unroll
        for (int n = 0; n < 2; ++n)
            bh[n] = SB[((wc * 2 + n) * 2 + s) * 64 + l];
#pragma unroll
        for (int m = 0; m < 4; ++m) {
            half8 ah = SA[((wr * 4 + m) * 2 + s) * 64 + l];
#pragma unroll
            for (int n = 0; n < 2; ++n)
                acc[m][n] = __builtin_amdgcn_mfma_f32_16x16x32_f16(ah, bh[n], acc[m][n], 0, 0, 0);
        }
    }

    // Epilogue: K_sum over 5 bandwidths via 1 exp2 + 3 muls + fma-folded k0.
    float part4[4] = {0.f, 0.f, 0.f, 0.f};
#pragma unroll
    for (int m = 0; m < 4; ++m)
#pragma unroll
        for (int n = 0; n < 2; ++n)
#pragma unroll
            for (int r = 0; r < 4; ++r) {
                float t0 = fmaf(acc[m][n][r], c2, nas[m][r] + nbv[n]);
                float k4 = __builtin_amdgcn_exp2f(t0);
                float k3 = k4 * k4;
                float k2 = k3 * k3;
                float k1 = k2 * k2;
                float s5 = fmaf(k1, k1, (k4 + k3) + (k2 + k1));  // k0 folded
                part4[r] += s5;
            }
    float part = (part4[0] + part4[1]) + (part4[2] + part4[3]);

#pragma unroll
    for (int off = 32; off; off >>= 1) part += __shfl_down(part, off, 64);
    if (l == 0) sred[w] = part;
    __syncthreads();
    if (t == 0) {
        float tot = ((sred[0] + sred[1]) + (sred[2] + sred[3])) +
                    ((sred[4] + sred[5]) + (sred[6] + sred[7]));
        float sgn = ((bi < 32) == (bj < 32)) ? 1.f : -1.f;
        float scl = (bi == bj) ? 1.f : 2.f;
        g_part[id] = (double)tot * (double)(sgn * scl);
    }
}

// Deterministic tree reduce of the 2080 per-pair doubles.
__global__ __launch_bounds__(256) void mmd_out(float* __restrict__ out) {
    __shared__ double wred[4];
    int t = threadIdx.x;
    double s = 0.0;
    for (int i = t; i < NPAIR; i += 256) s += g_part[i];
#pragma unroll
    for (int off = 32; off; off >>= 1) s += __shfl_down(s, off, 64);
    if ((t & 63) == 0) wred[t >> 6] = s;
    __syncthreads();
    if (t == 0)
        out[0] = (float)((wred[0] + wred[1] + wred[2] + wred[3]) * (1.0 / 16777216.0));
}

extern "C" void kernel_launch(void* const* d_in, const int* in_sizes, int n_in,
                              void* d_out, int out_size, void* d_ws, size_t ws_size,
                              hipStream_t stream) {
    const float* src = (const float*)d_in[0];
    const float* tgt = (const float*)d_in[1];
    float* out = (float*)d_out;

    mmd_prep<<<256, 256, 0, stream>>>(src, tgt);
    mmd_bw<<<1, 256, 0, stream>>>();
    mmd_main<<<NPAIR, 512, 0, stream>>>();
    mmd_out<<<1, 256, 0, stream>>>(out);
}

// Round 17
// 34.132 us; speedup vs baseline: 1.0538x; 1.0193x over previous
//
#include <hip/hip_runtime.h>
#include <math.h>

#define N_HALF 4096
#define D 64
#define M_TOT 8192
#define NPAIR 2080  // 64*65/2 upper-triangle 128x128 tile pairs

typedef _Float16 half8 __attribute__((ext_vector_type(8)));
typedef float f32x4 __attribute__((ext_vector_type(4)));

// Device-global scratch (fully rewritten by plain stores every call).
// R9 lesson: no per-block device fences / ticket counters.
__device__ _Float16 Fh[M_TOT * D];  // 1 MB fragment-major fp16 data
__device__ float g_norms[M_TOT];    // exact fp32 row norms
__device__ float g_pssq[256];       // per-prep-block sum-of-squares partials
__device__ float g_pcol[256 * D];   // per-prep-block column-sum partials
__device__ float g_coef;            // base exp2 coefficient g0
__device__ double g_part[NPAIR];    // per-pair signed partial sums

// Prep: fp16 convert into MFMA fragment-major layout + exact fp32 row norms
// + block partials for the bandwidth. Colsum partials via wave shuffles.
// Wave w covers k-half s = w&1 only -> cs[w] valid only in [s*32, s*32+32).
// F[rt][s][lane][e] = X[rt*16 + (lane&15)][s*32 + (lane>>4)*8 + e]
__global__ __launch_bounds__(256) void mmd_prep(const float* __restrict__ src,
                                                const float* __restrict__ tgt) {
    __shared__ float cs[4][D];  // per-wave column partials (half-valid each)
    __shared__ float hn[4][16];
    int t = threadIdx.x;
    int tid = blockIdx.x * 256 + t;  // 65536 threads total
    int l = t & 63;
    int rs = tid >> 6;
    int s = rs & 1, rt = rs >> 1;    // uniform per wave; s == (t>>6)&1
    int row = rt * 16 + (l & 15);
    int k0 = s * 32 + (l >> 4) * 8;
    const float* X = (row < N_HALF) ? src + (size_t)row * D
                                    : tgt + (size_t)(row - N_HALF) * D;
    float4 v0 = ((const float4*)(X + k0))[0];
    float4 v1 = ((const float4*)(X + k0))[1];
    float vs[8] = {v0.x, v0.y, v0.z, v0.w, v1.x, v1.y, v1.z, v1.w};
    half8 h;
    float p = 0.f;
#pragma unroll
    for (int e = 0; e < 8; ++e) {
        h[e] = (_Float16)vs[e];  // RNE
        p += vs[e] * vs[e];
    }
    ((half8*)Fh)[tid] = h;
    int w = t >> 6;
    // Column partials: reduce vs[e] over the 16 lanes sharing (l>>4) group.
    {
        float ce[8];
#pragma unroll
        for (int e = 0; e < 8; ++e) ce[e] = vs[e];
#pragma unroll
        for (int off = 1; off < 16; off <<= 1)
#pragma unroll
            for (int e = 0; e < 8; ++e) ce[e] += __shfl_xor(ce[e], off, 64);
        // lane l with l&15==0 holds the group's column sums for k0..k0+7
        if ((l & 15) == 0)
#pragma unroll
            for (int e = 0; e < 8; ++e) cs[w][k0 + e] = ce[e];
    }
    // Row norms: lanes l, l+16, l+32, l+48 share (row, s-half)
    p += __shfl_down(p, 32, 64);
    p += __shfl_down(p, 16, 64);
    if (l < 16) hn[w][l] = p;
    __syncthreads();
    if (t < 64) {
        float nr = 0.f;
        int tile = t >> 4, r = t & 15;
        if (t < 32) {
            nr = hn[tile * 2][r] + hn[tile * 2 + 1][r];
            g_norms[(blockIdx.x * 2 + tile) * 16 + r] = nr;
        }
        nr += __shfl_down(nr, 32, 64);
        nr += __shfl_down(nr, 16, 64);
        nr += __shfl_down(nr, 8, 64);
        nr += __shfl_down(nr, 4, 64);
        nr += __shfl_down(nr, 2, 64);
        nr += __shfl_down(nr, 1, 64);
        if (t == 0) g_pssq[blockIdx.x] = nr;
    }
    if (t < D) {
        // Columns 0-31 live in waves 0,2 (s=0); columns 32-63 in waves 1,3.
        float col = (t < 32) ? (cs[0][t] + cs[2][t]) : (cs[1][t] + cs[3][t]);
        g_pcol[blockIdx.x * D + t] = col;
    }
}

// Bandwidth coefficient, one small block (dedicated node -- per-block
// fusion regressed twice, R12/R15).
__global__ __launch_bounds__(256) void mmd_bw() {
    __shared__ float scol[4][64];
    __shared__ float sssq[4];
    int t = threadIdx.x, w = t >> 6, l = t & 63;
    float csum = 0.f;
#pragma unroll 16
    for (int q = 0; q < 64; ++q) csum += g_pcol[(w * 64 + q) * 64 + l];
    float sq = g_pssq[w * 64 + l];
#pragma unroll
    for (int off = 32; off; off >>= 1) sq += __shfl_xor(sq, off, 64);
    scol[w][l] = csum;
    if (l == 0) sssq[w] = sq;
    __syncthreads();
    if (t < 64) {
        float colsum = (scol[0][l] + scol[1][l]) + (scol[2][l] + scol[3][l]);
        float s2 = colsum * colsum;
#pragma unroll
        for (int off = 32; off; off >>= 1) s2 += __shfl_xor(s2, off, 64);
        if (t == 0) {
            float ssq = (sssq[0] + sssq[1]) + (sssq[2] + sssq[3]);
            const float M = (float)M_TOT;
            float sumL2 = 2.f * M * ssq - 2.f * s2;
            float bwq = sumL2 / (M * M - M) * 0.25f;  // / KERNEL_MUL^2
            g_coef = -1.4426950408889634f / (bwq * 16.f);
        }
    }
}

static __device__ inline void decode_pair(int id, int& bi, int& bj) {
    bi = (int)(64.5f - sqrtf(4160.25f - 2.0f * (float)id));
    while ((64 * (bi + 1) - ((bi + 1) * bi) / 2) <= id) ++bi;
    while ((64 * bi - (bi * (bi - 1)) / 2) > id) --bi;
    bj = bi + (id - (64 * bi - (bi * (bi - 1)) / 2));
}

// Main: one 128x128 pair tile per block, 8 waves of 64x32 each.
// XCD-chunked pair mapping: 2080 % 8 == 0 -> each XCD gets a contiguous
// run of 260 pair-ids (consecutive bi -> A-panel reuse in local L2).
// Fragments direct from L2 (LDS staging tested null, R16).
__global__ __launch_bounds__(512) void mmd_main() {
    __shared__ float sred[8];
    int t = threadIdx.x, w = t >> 6, l = t & 63;
    int wr = w >> 2, wc = w & 3;  // 2x4 wave grid: 64 rows x 32 cols per wave
    float g0 = g_coef;
    float c2 = -2.f * g0;
    const half8* FH = (const half8*)Fh;

    int id = (blockIdx.x & 7) * 260 + (blockIdx.x >> 3);  // XCD-chunked (bijective)
    int bi, bj;
    decode_pair(id, bi, bj);

    // Norm loads issued early, pre-scaled by g0 (consumed in epilogue).
    float nas[4][4];
#pragma unroll
    for (int m = 0; m < 4; ++m) {
        float4 v = *(const float4*)&g_norms[bi * 128 + wr * 64 + m * 16 + (l >> 4) * 4];
        nas[m][0] = v.x * g0; nas[m][1] = v.y * g0;
        nas[m][2] = v.z * g0; nas[m][3] = v.w * g0;
    }
    float nbv[2];
#pragma unroll
    for (int n = 0; n < 2; ++n)
        nbv[n] = g_norms[bj * 128 + wc * 32 + n * 16 + (l & 15)] * g0;

    f32x4 acc[4][2] = {};
#pragma unroll
    for (int s = 0; s < 2; ++s) {
        half8 bh[2];
#pragma unroll
        for (int n = 0; n < 2; ++n)
            bh[n] = FH[((bj * 8 + wc * 2 + n) * 2 + s) * 64 + l];
#pragma unroll
        for (int m = 0; m < 4; ++m) {
            half8 ah = FH[((bi * 8 + wr * 4 + m) * 2 + s) * 64 + l];
#pragma unroll
            for (int n = 0; n < 2; ++n)
                acc[m][n] = __builtin_amdgcn_mfma_f32_16x16x32_f16(ah, bh[n], acc[m][n], 0, 0, 0);
        }
    }

    // Epilogue: K_sum over 5 bandwidths via 1 exp2 + 3 muls + fma-folded k0.
    float part4[4] = {0.f, 0.f, 0.f, 0.f};
#pragma unroll
    for (int m = 0; m < 4; ++m)
#pragma unroll
        for (int n = 0; n < 2; ++n)
#pragma unroll
            for (int r = 0; r < 4; ++r) {
                float t0 = fmaf(acc[m][n][r], c2, nas[m][r] + nbv[n]);
                float k4 = __builtin_amdgcn_exp2f(t0);
                float k3 = k4 * k4;
                float k2 = k3 * k3;
                float k1 = k2 * k2;
                float s5 = fmaf(k1, k1, (k4 + k3) + (k2 + k1));  // k0 folded
                part4[r] += s5;
            }
    float part = (part4[0] + part4[1]) + (part4[2] + part4[3]);

#pragma unroll
    for (int off = 32; off; off >>= 1) part += __shfl_down(part, off, 64);
    if (l == 0) sred[w] = part;
    __syncthreads();
    if (t == 0) {
        float tot = ((sred[0] + sred[1]) + (sred[2] + sred[3])) +
                    ((sred[4] + sred[5]) + (sred[6] + sred[7]));
        float sgn = ((bi < 32) == (bj < 32)) ? 1.f : -1.f;
        float scl = (bi == bj) ? 1.f : 2.f;
        g_part[id] = (double)tot * (double)(sgn * scl);
    }
}

// Deterministic tree reduce of the 2080 per-pair doubles.
__global__ __launch_bounds__(256) void mmd_out(float* __restrict__ out) {
    __shared__ double wred[4];
    int t = threadIdx.x;
    double s = 0.0;
    for (int i = t; i < NPAIR; i += 256) s += g_part[i];
#pragma unroll
    for (int off = 32; off; off >>= 1) s += __shfl_down(s, off, 64);
    if ((t & 63) == 0) wred[t >> 6] = s;
    __syncthreads();
    if (t == 0)
        out[0] = (float)((wred[0] + wred[1] + wred[2] + wred[3]) * (1.0 / 16777216.0));
}

extern "C" void kernel_launch(void* const* d_in, const int* in_sizes, int n_in,
                              void* d_out, int out_size, void* d_ws, size_t ws_size,
                              hipStream_t stream) {
    const float* src = (const float*)d_in[0];
    const float* tgt = (const float*)d_in[1];
    float* out = (float*)d_out;

    mmd_prep<<<256, 256, 0, stream>>>(src, tgt);
    mmd_bw<<<1, 256, 0, stream>>>();
    mmd_main<<<NPAIR, 512, 0, stream>>>();
    mmd_out<<<1, 256, 0, stream>>>(out);
}